// Round 1
// baseline (655.264 us; speedup 1.0000x reference)
//
#include <hip/hip_runtime.h>
#include <hip/hip_bf16.h>
#include <math.h>

typedef __attribute__((ext_vector_type(8))) __bf16 bf16x8;
typedef __attribute__((ext_vector_type(4))) float f32x4;

#define BM 128
#define BN 128
#define BK 64

__device__ __forceinline__ void glds16(const void* g, void* l) {
  __builtin_amdgcn_global_load_lds(
      (const __attribute__((address_space(1))) void*)g,
      (__attribute__((address_space(3))) void*)l, 16, 0, 0);
}

__device__ __forceinline__ unsigned short f2bf(float f) {
  __hip_bfloat16 h = __float2bfloat16(f);
  return __builtin_bit_cast(unsigned short, h);
}

// ---------------- Kernel 1: per-token int8 fake-quant -> bf16 ----------------
// one block (256 thr) per token row; I = 4096 floats = 1024 float4
__global__ void quant_rows(const float* __restrict__ x, ushort* __restrict__ xq,
                           int I) {
  const int row = blockIdx.x;
  const int tid = threadIdx.x;
  const float4* xr = (const float4*)(x + (size_t)row * I);
  float4 v[4];
  float mn = 0.f, mx = 0.f;  // reference clamps min<=0, max>=0
#pragma unroll
  for (int i = 0; i < 4; ++i) {
    v[i] = xr[tid + i * 256];
    mn = fminf(mn, fminf(fminf(v[i].x, v[i].y), fminf(v[i].z, v[i].w)));
    mx = fmaxf(mx, fmaxf(fmaxf(v[i].x, v[i].y), fmaxf(v[i].z, v[i].w)));
  }
#pragma unroll
  for (int off = 32; off > 0; off >>= 1) {
    mn = fminf(mn, __shfl_down(mn, off));
    mx = fmaxf(mx, __shfl_down(mx, off));
  }
  __shared__ float smn[4], smx[4], sp[2];
  const int wave = tid >> 6, lane = tid & 63;
  if (lane == 0) { smn[wave] = mn; smx[wave] = mx; }
  __syncthreads();
  if (tid == 0) {
    mn = fminf(fminf(smn[0], smn[1]), fminf(smn[2], smn[3]));
    mx = fmaxf(fmaxf(smx[0], smx[1]), fmaxf(smx[2], smx[3]));
    float scale = fmaxf((mx - mn) / 255.0f, 1.1920928955078125e-07f);
    float dmin = mn / scale, dmax = mx / scale;
    float zp = ((-128.0f + dmin) + (127.0f + dmax) > 0.0f) ? (-128.0f - dmin)
                                                           : (127.0f - dmax);
    zp = rintf(fminf(fmaxf(zp, -128.0f), 127.0f));  // jnp.round = RNE
    sp[0] = scale;
    sp[1] = zp;
  }
  __syncthreads();
  const float scale = sp[0], zp = sp[1];
  ushort4* xo = (ushort4*)(xq + (size_t)row * I);
#pragma unroll
  for (int i = 0; i < 4; ++i) {
    ushort4 o;
    float q;
    q = fminf(fmaxf(rintf(v[i].x / scale) + zp, -128.f), 127.f);
    o.x = f2bf((q - zp) * scale);
    q = fminf(fmaxf(rintf(v[i].y / scale) + zp, -128.f), 127.f);
    o.y = f2bf((q - zp) * scale);
    q = fminf(fmaxf(rintf(v[i].z / scale) + zp, -128.f), 127.f);
    o.z = f2bf((q - zp) * scale);
    q = fminf(fmaxf(rintf(v[i].w / scale) + zp, -128.f), 127.f);
    o.w = f2bf((q - zp) * scale);
    xo[tid + i * 256] = o;
  }
}

// ---------------- Kernel 2: groupwise int4 weight dequant -> bf16 -----------
// one block (256 thr) per output row o; thread handles 4 consecutive elems x4
__global__ void dequant_w(const int* __restrict__ w,
                          const float* __restrict__ scales,
                          const float* __restrict__ zeros,
                          ushort* __restrict__ wq, int I, int G) {
  const int o = blockIdx.x;
  const int tid = threadIdx.x;
  const int4* wr = (const int4*)(w + (size_t)o * I);
  ushort4* wo = (ushort4*)(wq + (size_t)o * I);
#pragma unroll
  for (int it = 0; it < 4; ++it) {
    const int chunk = it * 256 + tid;    // chunk of 4 elements
    const int g = chunk >> 6;            // (chunk*4)/256
    const float s = scales[(size_t)o * G + g];
    const float z = zeros[(size_t)o * G + g];
    const int4 wv = wr[chunk];
    ushort4 ov;
    ov.x = f2bf(((float)wv.x - z) * s);
    ov.y = f2bf(((float)wv.y - z) * s);
    ov.z = f2bf(((float)wv.z - z) * s);
    ov.w = f2bf(((float)wv.w - z) * s);
    wo[chunk] = ov;
  }
}

// ---------------- Kernel 3: bf16 NT GEMM (m97 recipe) -----------------------
// C[M,N] = A[M,K] * B[N,K]^T ; 128x128 tile, BK=64, 4 waves, 4x4 MFMA/wave
__global__ __launch_bounds__(256) void gemm_bt(const ushort* __restrict__ A,
                                               const ushort* __restrict__ B,
                                               float* __restrict__ C, int M,
                                               int N, int K) {
  __shared__ __align__(16) ushort As[BM * BK];
  __shared__ __align__(16) ushort Bs[BN * BK];
  const int tid = threadIdx.x;
  const int wave = tid >> 6, lane = tid & 63;
  const int wm = (wave >> 1) * 64, wn = (wave & 1) * 64;
  const int bm0 = blockIdx.y * BM, bn0 = blockIdx.x * BN;

  // staging: lane l loads 16B at row (l>>3), kchunk (l&7) -> LDS offset l*16
  const int ldr = lane >> 3;
  const int ldk = (lane & 7) * 8;
  const ushort* Ag = A + (size_t)(bm0 + wave * 32 + ldr) * K + ldk;
  const ushort* Bg = B + (size_t)(bn0 + wave * 32 + ldr) * K + ldk;
  ushort* Asw = &As[(wave * 32) * BK];
  ushort* Bsw = &Bs[(wave * 32) * BK];

  f32x4 acc[4][4];
#pragma unroll
  for (int i = 0; i < 4; ++i)
#pragma unroll
    for (int j = 0; j < 4; ++j) acc[i][j] = (f32x4){0.f, 0.f, 0.f, 0.f};

  const int mrow = lane & 15;       // M/N index within 16-tile
  const int kq = (lane >> 4) * 8;   // K offset of this lane's 8 elems

  for (int k0 = 0; k0 < K; k0 += BK) {
#pragma unroll
    for (int it = 0; it < 4; ++it) {
      glds16(Ag + (size_t)(it * 8) * K + k0, Asw + (it * 8) * BK);
      glds16(Bg + (size_t)(it * 8) * K + k0, Bsw + (it * 8) * BK);
    }
    __syncthreads();
#pragma unroll
    for (int ks = 0; ks < 2; ++ks) {
      const int kb = ks * 32 + kq;
      bf16x8 af[4], bfv[4];
#pragma unroll
      for (int i = 0; i < 4; ++i) {
        af[i] = *(const bf16x8*)&As[(wm + i * 16 + mrow) * BK + kb];
        bfv[i] = *(const bf16x8*)&Bs[(wn + i * 16 + mrow) * BK + kb];
      }
#pragma unroll
      for (int i = 0; i < 4; ++i)
#pragma unroll
        for (int j = 0; j < 4; ++j)
          acc[i][j] = __builtin_amdgcn_mfma_f32_16x16x32_bf16(
              af[i], bfv[j], acc[i][j], 0, 0, 0);
    }
    __syncthreads();
  }

  // epilogue: C/D layout col=lane&15, row=(lane>>4)*4+reg
  const int col = lane & 15;
  const int rq = (lane >> 4) * 4;
#pragma unroll
  for (int i = 0; i < 4; ++i)
#pragma unroll
    for (int j = 0; j < 4; ++j) {
      const int r0 = bm0 + wm + i * 16 + rq;
      const int c = bn0 + wn + j * 16 + col;
#pragma unroll
      for (int r = 0; r < 4; ++r)
        C[(size_t)(r0 + r) * N + c] = acc[i][j][r];
    }
}

extern "C" void kernel_launch(void* const* d_in, const int* in_sizes, int n_in,
                              void* d_out, int out_size, void* d_ws,
                              size_t ws_size, hipStream_t stream) {
  const float* x = (const float*)d_in[0];
  const int* w = (const int*)d_in[1];
  const float* scales = (const float*)d_in[2];
  const float* zeros = (const float*)d_in[3];
  float* out = (float*)d_out;

  // derive shapes: in_sizes[0]=T*I, in_sizes[1]=O*I, out_size=T*O
  const double ii =
      sqrt((double)in_sizes[0] * (double)in_sizes[1] / (double)out_size);
  const int I = (int)(ii + 0.5);
  const int T = in_sizes[0] / I;
  const int O = in_sizes[1] / I;
  const int G = I / 256;

  ushort* xq = (ushort*)d_ws;                 // T*I bf16
  ushort* wq = xq + (size_t)T * I;            // O*I bf16

  quant_rows<<<T, 256, 0, stream>>>(x, xq, I);
  dequant_w<<<O, 256, 0, stream>>>(w, scales, zeros, wq, I, G);
  gemm_bt<<<dim3(O / BN, T / BM), 256, 0, stream>>>(xq, wq, out, T, O, I);
}

// Round 2
// 594.755 us; speedup vs baseline: 1.1017x; 1.1017x over previous
//
#include <hip/hip_runtime.h>
#include <hip/hip_bf16.h>
#include <math.h>

typedef __attribute__((ext_vector_type(8))) __bf16 bf16x8;
typedef __attribute__((ext_vector_type(4))) float f32x4;

#define BM 128
#define BN 128
#define BK 64

__device__ __forceinline__ void glds16(const void* g, void* l) {
  __builtin_amdgcn_global_load_lds(
      (const __attribute__((address_space(1))) void*)g,
      (__attribute__((address_space(3))) void*)l, 16, 0, 0);
}

__device__ __forceinline__ unsigned short f2bf(float f) {
  __hip_bfloat16 h = __float2bfloat16(f);
  return __builtin_bit_cast(unsigned short, h);
}

// ---------------- Kernel 1: per-token int8 fake-quant -> bf16 ----------------
// one block (256 thr) per token row; I = 4096 floats = 1024 float4
__global__ void quant_rows(const float* __restrict__ x, ushort* __restrict__ xq,
                           int I) {
  const int row = blockIdx.x;
  const int tid = threadIdx.x;
  const float4* xr = (const float4*)(x + (size_t)row * I);
  float4 v[4];
  float mn = 0.f, mx = 0.f;  // reference clamps min<=0, max>=0
#pragma unroll
  for (int i = 0; i < 4; ++i) {
    v[i] = xr[tid + i * 256];
    mn = fminf(mn, fminf(fminf(v[i].x, v[i].y), fminf(v[i].z, v[i].w)));
    mx = fmaxf(mx, fmaxf(fmaxf(v[i].x, v[i].y), fmaxf(v[i].z, v[i].w)));
  }
#pragma unroll
  for (int off = 32; off > 0; off >>= 1) {
    mn = fminf(mn, __shfl_down(mn, off));
    mx = fmaxf(mx, __shfl_down(mx, off));
  }
  __shared__ float smn[4], smx[4], sp[3];
  const int wave = tid >> 6, lane = tid & 63;
  if (lane == 0) { smn[wave] = mn; smx[wave] = mx; }
  __syncthreads();
  if (tid == 0) {
    mn = fminf(fminf(smn[0], smn[1]), fminf(smn[2], smn[3]));
    mx = fmaxf(fmaxf(smx[0], smx[1]), fmaxf(smx[2], smx[3]));
    float scale = fmaxf((mx - mn) / 255.0f, 1.1920928955078125e-07f);
    float dmin = mn / scale, dmax = mx / scale;
    float zp = ((-128.0f + dmin) + (127.0f + dmax) > 0.0f) ? (-128.0f - dmin)
                                                           : (127.0f - dmax);
    zp = rintf(fminf(fmaxf(zp, -128.0f), 127.0f));  // jnp.round = RNE
    sp[0] = scale;
    sp[1] = zp;
    sp[2] = 1.0f / scale;
  }
  __syncthreads();
  const float scale = sp[0], zp = sp[1], rs = sp[2];
  ushort4* xo = (ushort4*)(xq + (size_t)row * I);
#pragma unroll
  for (int i = 0; i < 4; ++i) {
    ushort4 o;
    float q;
    q = fminf(fmaxf(rintf(v[i].x * rs) + zp, -128.f), 127.f);
    o.x = f2bf((q - zp) * scale);
    q = fminf(fmaxf(rintf(v[i].y * rs) + zp, -128.f), 127.f);
    o.y = f2bf((q - zp) * scale);
    q = fminf(fmaxf(rintf(v[i].z * rs) + zp, -128.f), 127.f);
    o.z = f2bf((q - zp) * scale);
    q = fminf(fmaxf(rintf(v[i].w * rs) + zp, -128.f), 127.f);
    o.w = f2bf((q - zp) * scale);
    xo[tid + i * 256] = o;
  }
}

// ---------------- Kernel 2: groupwise int4 weight dequant -> bf16 -----------
__global__ void dequant_w(const int* __restrict__ w,
                          const float* __restrict__ scales,
                          const float* __restrict__ zeros,
                          ushort* __restrict__ wq, int I, int G) {
  const int o = blockIdx.x;
  const int tid = threadIdx.x;
  const int4* wr = (const int4*)(w + (size_t)o * I);
  ushort4* wo = (ushort4*)(wq + (size_t)o * I);
#pragma unroll
  for (int it = 0; it < 4; ++it) {
    const int chunk = it * 256 + tid;    // chunk of 4 elements
    const int g = chunk >> 6;            // (chunk*4)/256
    const float s = scales[(size_t)o * G + g];
    const float z = zeros[(size_t)o * G + g];
    const int4 wv = wr[chunk];
    ushort4 ov;
    ov.x = f2bf(((float)wv.x - z) * s);
    ov.y = f2bf(((float)wv.y - z) * s);
    ov.z = f2bf(((float)wv.z - z) * s);
    ov.w = f2bf(((float)wv.w - z) * s);
    wo[chunk] = ov;
  }
}

// ---------------- Kernel 3: bf16 NT GEMM, XOR-swizzled LDS ------------------
// C[M,N] = A[M,K] * B[N,K]^T ; 128x128 tile, BK=64, 4 waves, 4x4 MFMA/wave
// LDS physical chunk c (16B) of row r holds logical k-chunk (c ^ (r&7)):
// staging lane l fetches global chunk ((l&7) ^ (l>>3)) so global_load_lds'
// wave-uniform-base+lane*16 dest produces exactly that layout; fragment
// reads XOR with (row&7) -> all 32 banks covered, zero conflict cycles.
__global__ __launch_bounds__(256) void gemm_bt(const ushort* __restrict__ A,
                                               const ushort* __restrict__ B,
                                               float* __restrict__ C, int M,
                                               int N, int K) {
  __shared__ __align__(16) ushort As[BM * BK];
  __shared__ __align__(16) ushort Bs[BN * BK];
  const int tid = threadIdx.x;
  const int wave = tid >> 6, lane = tid & 63;
  const int wm = (wave >> 1) * 64, wn = (wave & 1) * 64;
  const int bm0 = blockIdx.y * BM, bn0 = blockIdx.x * BN;

  // staging: lane l covers row (l>>3) of an 8-row slab, physical chunk (l&7),
  // which must hold logical chunk (l&7) ^ (row&7) = (l&7) ^ (l>>3)
  const int ldr = lane >> 3;
  const int ldk = ((lane & 7) ^ ldr) * 8;
  const ushort* Ag = A + (size_t)(bm0 + wave * 32 + ldr) * K + ldk;
  const ushort* Bg = B + (size_t)(bn0 + wave * 32 + ldr) * K + ldk;
  ushort* Asw = &As[(wave * 32) * BK];
  ushort* Bsw = &Bs[(wave * 32) * BK];

  f32x4 acc[4][4];
#pragma unroll
  for (int i = 0; i < 4; ++i)
#pragma unroll
    for (int j = 0; j < 4; ++j) acc[i][j] = (f32x4){0.f, 0.f, 0.f, 0.f};

  const int mrow = lane & 15;      // M/N index within 16-tile
  const int kc = lane >> 4;        // logical k-chunk (16B) within 32-k step
  const int sw = mrow & 7;         // row-phase for the XOR swizzle

  for (int k0 = 0; k0 < K; k0 += BK) {
#pragma unroll
    for (int it = 0; it < 4; ++it) {
      glds16(Ag + (size_t)(it * 8) * K + k0, Asw + (it * 8) * BK);
      glds16(Bg + (size_t)(it * 8) * K + k0, Bsw + (it * 8) * BK);
    }
    __syncthreads();
#pragma unroll
    for (int ks = 0; ks < 2; ++ks) {
      const int chunk = ((ks * 4 + kc) ^ sw) * 8;  // swizzled 16B chunk
      bf16x8 af[4], bfv[4];
#pragma unroll
      for (int i = 0; i < 4; ++i) {
        af[i] = *(const bf16x8*)&As[(wm + i * 16 + mrow) * BK + chunk];
        bfv[i] = *(const bf16x8*)&Bs[(wn + i * 16 + mrow) * BK + chunk];
      }
#pragma unroll
      for (int i = 0; i < 4; ++i)
#pragma unroll
        for (int j = 0; j < 4; ++j)
          acc[i][j] = __builtin_amdgcn_mfma_f32_16x16x32_bf16(
              af[i], bfv[j], acc[i][j], 0, 0, 0);
    }
    __syncthreads();
  }

  // epilogue: C/D layout col=lane&15, row=(lane>>4)*4+reg
  const int col = lane & 15;
  const int rq = (lane >> 4) * 4;
#pragma unroll
  for (int i = 0; i < 4; ++i)
#pragma unroll
    for (int j = 0; j < 4; ++j) {
      const int r0 = bm0 + wm + i * 16 + rq;
      const int c = bn0 + wn + j * 16 + col;
#pragma unroll
      for (int r = 0; r < 4; ++r)
        C[(size_t)(r0 + r) * N + c] = acc[i][j][r];
    }
}

extern "C" void kernel_launch(void* const* d_in, const int* in_sizes, int n_in,
                              void* d_out, int out_size, void* d_ws,
                              size_t ws_size, hipStream_t stream) {
  const float* x = (const float*)d_in[0];
  const int* w = (const int*)d_in[1];
  const float* scales = (const float*)d_in[2];
  const float* zeros = (const float*)d_in[3];
  float* out = (float*)d_out;

  // derive shapes: in_sizes[0]=T*I, in_sizes[1]=O*I, out_size=T*O
  const double ii =
      sqrt((double)in_sizes[0] * (double)in_sizes[1] / (double)out_size);
  const int I = (int)(ii + 0.5);
  const int T = in_sizes[0] / I;
  const int O = in_sizes[1] / I;
  const int G = I / 256;

  ushort* xq = (ushort*)d_ws;                 // T*I bf16
  ushort* wq = xq + (size_t)T * I;            // O*I bf16

  quant_rows<<<T, 256, 0, stream>>>(x, xq, I);
  dequant_w<<<O, 256, 0, stream>>>(w, scales, zeros, wq, I, G);
  gemm_bt<<<dim3(O / BN, T / BM), 256, 0, stream>>>(xq, wq, out, T, O, I);
}

// Round 3
// 587.260 us; speedup vs baseline: 1.1158x; 1.0128x over previous
//
#include <hip/hip_runtime.h>
#include <hip/hip_bf16.h>
#include <math.h>

typedef __attribute__((ext_vector_type(8))) __bf16 bf16x8;
typedef __attribute__((ext_vector_type(4))) float f32x4;

#define BM 128
#define BN 128
#define BK 64

__device__ __forceinline__ void glds16(const void* g, void* l) {
  __builtin_amdgcn_global_load_lds(
      (const __attribute__((address_space(1))) void*)g,
      (__attribute__((address_space(3))) void*)l, 16, 0, 0);
}

__device__ __forceinline__ unsigned short f2bf(float f) {
  __hip_bfloat16 h = __float2bfloat16(f);
  return __builtin_bit_cast(unsigned short, h);
}

// ---------------- Fused prep: per-token quant (blocks [0,T)) ----------------
// ----------------        + groupwise weight dequant (blocks [T,T+O)) -------
// Fusing into one launch lets the two independent memory streams run
// concurrently (single stream would serialize the dispatches) and pays one
// ramp-up/ramp-down instead of two.
__global__ void prep_fused(const float* __restrict__ x,
                           ushort* __restrict__ xq, int T,
                           const int* __restrict__ w,
                           const float* __restrict__ scales,
                           const float* __restrict__ zeros,
                           ushort* __restrict__ wq, int I, int G) {
  const int tid = threadIdx.x;
  if (blockIdx.x < (unsigned)T) {
    // ---- per-token int8 fake-quant -> bf16 (one block per token row) ----
    const int row = blockIdx.x;
    const float4* xr = (const float4*)(x + (size_t)row * I);
    float4 v[4];
    float mn = 0.f, mx = 0.f;  // reference clamps min<=0, max>=0
#pragma unroll
    for (int i = 0; i < 4; ++i) {
      v[i] = xr[tid + i * 256];
      mn = fminf(mn, fminf(fminf(v[i].x, v[i].y), fminf(v[i].z, v[i].w)));
      mx = fmaxf(mx, fmaxf(fmaxf(v[i].x, v[i].y), fmaxf(v[i].z, v[i].w)));
    }
#pragma unroll
    for (int off = 32; off > 0; off >>= 1) {
      mn = fminf(mn, __shfl_down(mn, off));
      mx = fmaxf(mx, __shfl_down(mx, off));
    }
    __shared__ float smn[4], smx[4], sp[3];
    const int wave = tid >> 6, lane = tid & 63;
    if (lane == 0) { smn[wave] = mn; smx[wave] = mx; }
    __syncthreads();
    if (tid == 0) {
      mn = fminf(fminf(smn[0], smn[1]), fminf(smn[2], smn[3]));
      mx = fmaxf(fmaxf(smx[0], smx[1]), fmaxf(smx[2], smx[3]));
      float scale = fmaxf((mx - mn) / 255.0f, 1.1920928955078125e-07f);
      float dmin = mn / scale, dmax = mx / scale;
      float zp = ((-128.0f + dmin) + (127.0f + dmax) > 0.0f)
                     ? (-128.0f - dmin)
                     : (127.0f - dmax);
      zp = rintf(fminf(fmaxf(zp, -128.0f), 127.0f));  // jnp.round = RNE
      sp[0] = scale;
      sp[1] = zp;
      sp[2] = 1.0f / scale;
    }
    __syncthreads();
    const float scale = sp[0], zp = sp[1], rs = sp[2];
    ushort4* xo = (ushort4*)(xq + (size_t)row * I);
#pragma unroll
    for (int i = 0; i < 4; ++i) {
      ushort4 o;
      float q;
      q = fminf(fmaxf(rintf(v[i].x * rs) + zp, -128.f), 127.f);
      o.x = f2bf((q - zp) * scale);
      q = fminf(fmaxf(rintf(v[i].y * rs) + zp, -128.f), 127.f);
      o.y = f2bf((q - zp) * scale);
      q = fminf(fmaxf(rintf(v[i].z * rs) + zp, -128.f), 127.f);
      o.z = f2bf((q - zp) * scale);
      q = fminf(fmaxf(rintf(v[i].w * rs) + zp, -128.f), 127.f);
      o.w = f2bf((q - zp) * scale);
      xo[tid + i * 256] = o;
    }
  } else {
    // ---- groupwise int4 weight dequant -> bf16 (one block per out row) ----
    const int o = blockIdx.x - T;
    const int4* wr = (const int4*)(w + (size_t)o * I);
    ushort4* wo = (ushort4*)(wq + (size_t)o * I);
#pragma unroll
    for (int it = 0; it < 4; ++it) {
      const int chunk = it * 256 + tid;  // chunk of 4 elements
      const int g = chunk >> 6;          // (chunk*4)/256
      const float s = scales[(size_t)o * G + g];
      const float z = zeros[(size_t)o * G + g];
      const int4 wv = wr[chunk];
      ushort4 ov;
      ov.x = f2bf(((float)wv.x - z) * s);
      ov.y = f2bf(((float)wv.y - z) * s);
      ov.z = f2bf(((float)wv.z - z) * s);
      ov.w = f2bf(((float)wv.w - z) * s);
      wo[chunk] = ov;
    }
  }
}

// ---------------- bf16 NT GEMM, XOR-swizzled LDS (unchanged, R2) ------------
// C[M,N] = A[M,K] * B[N,K]^T ; 128x128 tile, BK=64, 4 waves, 4x4 MFMA/wave
// LDS physical chunk c (16B) of row r holds logical k-chunk (c ^ (r&7)):
// staging lane l fetches global chunk ((l&7) ^ (l>>3)) so global_load_lds'
// wave-uniform-base+lane*16 dest produces exactly that layout; fragment
// reads XOR with (row&7) -> all 32 banks covered, zero conflict cycles.
__global__ __launch_bounds__(256) void gemm_bt(const ushort* __restrict__ A,
                                               const ushort* __restrict__ B,
                                               float* __restrict__ C, int M,
                                               int N, int K) {
  __shared__ __align__(16) ushort As[BM * BK];
  __shared__ __align__(16) ushort Bs[BN * BK];
  const int tid = threadIdx.x;
  const int wave = tid >> 6, lane = tid & 63;
  const int wm = (wave >> 1) * 64, wn = (wave & 1) * 64;
  const int bm0 = blockIdx.y * BM, bn0 = blockIdx.x * BN;

  const int ldr = lane >> 3;
  const int ldk = ((lane & 7) ^ ldr) * 8;
  const ushort* Ag = A + (size_t)(bm0 + wave * 32 + ldr) * K + ldk;
  const ushort* Bg = B + (size_t)(bn0 + wave * 32 + ldr) * K + ldk;
  ushort* Asw = &As[(wave * 32) * BK];
  ushort* Bsw = &Bs[(wave * 32) * BK];

  f32x4 acc[4][4];
#pragma unroll
  for (int i = 0; i < 4; ++i)
#pragma unroll
    for (int j = 0; j < 4; ++j) acc[i][j] = (f32x4){0.f, 0.f, 0.f, 0.f};

  const int mrow = lane & 15;  // M/N index within 16-tile
  const int kc = lane >> 4;    // logical k-chunk (16B) within 32-k step
  const int sw = mrow & 7;     // row-phase for the XOR swizzle

  for (int k0 = 0; k0 < K; k0 += BK) {
#pragma unroll
    for (int it = 0; it < 4; ++it) {
      glds16(Ag + (size_t)(it * 8) * K + k0, Asw + (it * 8) * BK);
      glds16(Bg + (size_t)(it * 8) * K + k0, Bsw + (it * 8) * BK);
    }
    __syncthreads();
#pragma unroll
    for (int ks = 0; ks < 2; ++ks) {
      const int chunk = ((ks * 4 + kc) ^ sw) * 8;  // swizzled 16B chunk
      bf16x8 af[4], bfv[4];
#pragma unroll
      for (int i = 0; i < 4; ++i) {
        af[i] = *(const bf16x8*)&As[(wm + i * 16 + mrow) * BK + chunk];
        bfv[i] = *(const bf16x8*)&Bs[(wn + i * 16 + mrow) * BK + chunk];
      }
#pragma unroll
      for (int i = 0; i < 4; ++i)
#pragma unroll
        for (int j = 0; j < 4; ++j)
          acc[i][j] = __builtin_amdgcn_mfma_f32_16x16x32_bf16(
              af[i], bfv[j], acc[i][j], 0, 0, 0);
    }
    __syncthreads();
  }

  // epilogue: C/D layout col=lane&15, row=(lane>>4)*4+reg
  const int col = lane & 15;
  const int rq = (lane >> 4) * 4;
#pragma unroll
  for (int i = 0; i < 4; ++i)
#pragma unroll
    for (int j = 0; j < 4; ++j) {
      const int r0 = bm0 + wm + i * 16 + rq;
      const int c = bn0 + wn + j * 16 + col;
#pragma unroll
      for (int r = 0; r < 4; ++r)
        C[(size_t)(r0 + r) * N + c] = acc[i][j][r];
    }
}

extern "C" void kernel_launch(void* const* d_in, const int* in_sizes, int n_in,
                              void* d_out, int out_size, void* d_ws,
                              size_t ws_size, hipStream_t stream) {
  const float* x = (const float*)d_in[0];
  const int* w = (const int*)d_in[1];
  const float* scales = (const float*)d_in[2];
  const float* zeros = (const float*)d_in[3];
  float* out = (float*)d_out;

  // derive shapes: in_sizes[0]=T*I, in_sizes[1]=O*I, out_size=T*O
  const double ii =
      sqrt((double)in_sizes[0] * (double)in_sizes[1] / (double)out_size);
  const int I = (int)(ii + 0.5);
  const int T = in_sizes[0] / I;
  const int O = in_sizes[1] / I;
  const int G = I / 256;

  ushort* xq = (ushort*)d_ws;       // T*I bf16
  ushort* wq = xq + (size_t)T * I;  // O*I bf16

  prep_fused<<<T + O, 256, 0, stream>>>(x, xq, T, w, scales, zeros, wq, I, G);
  gemm_bt<<<dim3(O / BN, T / BM), 256, 0, stream>>>(xq, wq, out, T, O, I);
}